// Round 7
// baseline (83.723 us; speedup 1.0000x reference)
//
#include <hip/hip_runtime.h>
#include <math.h>

#define HEADS 8
#define C 256
#define NUM_STAR 4
#define SLOTS 32              // NUM_STAR * HEADS
#define RSQRT_DH 0.17677669529663688f   // 1/sqrt(32)
#define LN_EPS 1e-5f
#define PF 24                 // fused-kernel partitions per graph (grid = G*PF = 768)
#define CWK 8                 // nodes per wave chunk
#define RND 32                // nodes per round (4 waves x 8)
#define XB 264                // x_nc row stride (ushorts)
#define ST 40                 // x_cn row stride (ushorts): 32 nodes + 8 pad
#define EP 40                 // e_t row stride (ushorts)

// LDS layout (ushort offsets) in ONE array so x_nc over-reads stay in-bounds
#define X_NC 0                // 4*CWK*XB = 8448
#define X_CN 8448             // C*ST = 10240
#define E_OFF 18688           // SLOTS*EP = 1280
#define LDS_TOT 19968         // 39,936 B -> 3 blocks/CU

typedef __attribute__((ext_vector_type(8))) short short8;    // bf16x8 MFMA operand
typedef __attribute__((ext_vector_type(4))) float floatx4;   // f32x4 MFMA accum

// f32 -> bf16 (RNE) top-16 (scalar)
__device__ __forceinline__ unsigned int f2b(float f) {
    unsigned int u = __float_as_uint(f);
    return (u + 0x7fffu + ((u >> 16) & 1u)) >> 16;
}
// packed f32x2 -> bf16x2 (RNE)
__device__ __forceinline__ unsigned int pk_bf16(float lo, float hi) {
    unsigned int r;
    asm("v_cvt_pk_bf16_f32 %0, %1, %2" : "=v"(r) : "v"(lo), "v"(hi));
    return r;
}
__device__ __forceinline__ float fcomp(const float4& v, int jj) {
    return jj == 0 ? v.x : jj == 1 ? v.y : jj == 2 ? v.z : v.w;
}
// raw barrier: LDS-visible, does NOT drain vmcnt
__device__ __forceinline__ void block_sync_lds() {
    asm volatile("s_waitcnt lgkmcnt(0)" ::: "memory");
    __builtin_amdgcn_sched_barrier(0);
    __builtin_amdgcn_s_barrier();
    __builtin_amdgcn_sched_barrier(0);
}

// ---------------- star prep (+ gstart fold in last block) -------------------
__global__ void k_star_prep(const float* __restrict__ stars,
                            const float* __restrict__ Wq_w, const float* __restrict__ Wq_b,
                            const float* __restrict__ Wk_w, const float* __restrict__ Wk_b,
                            unsigned short* __restrict__ U16, float* __restrict__ eself,
                            float* __restrict__ denom,
                            const int* __restrict__ batch, int N, int G,
                            int* __restrict__ gstart) {
    if (blockIdx.x == gridDim.x - 1) {       // gstart block
        int g = threadIdx.x;
        if (g > G) return;
        if (g == 0) { gstart[0] = 0; return; }
        if (g == G) { gstart[G] = N; return; }
        int lo = 0, hi = N;
        while (lo < hi) {
            int mid = (lo + hi) >> 1;
            if (batch[mid] < g) lo = mid + 1; else hi = mid;
        }
        gstart[g] = lo;
        return;
    }

    __shared__ float xs[C];
    __shared__ float qv[C];
    __shared__ float kv[C];
    const int gs = blockIdx.x;           // g*4 + s
    const int g = gs >> 2, s = gs & 3;
    const int t = threadIdx.x;

    xs[t] = stars[gs * C + t];
    __syncthreads();

    float aq = Wq_b[t], ak = Wk_b[t];
    const float* wq = Wq_w + (size_t)t * C;
    const float* wk = Wk_w + (size_t)t * C;
    #pragma unroll 4
    for (int j = 0; j < C; j += 4) {
        float4 x4 = *(const float4*)(xs + j);
        float4 a4 = *(const float4*)(wq + j);
        aq += a4.x * x4.x + a4.y * x4.y + a4.z * x4.z + a4.w * x4.w;
        float4 b4 = *(const float4*)(wk + j);
        ak += b4.x * x4.x + b4.y * x4.y + b4.z * x4.z + b4.w * x4.w;
    }
    qv[t] = aq; kv[t] = ak;
    __syncthreads();

    {   // self score per head
        float p = qv[t] * kv[t];
        #pragma unroll
        for (int off = 16; off; off >>= 1) p += __shfl_down(p, off, 32);
        if ((t & 31) == 0) {
            int h = t >> 5;
            float e = __expf(p * RSQRT_DH);
            eself[g * SLOTS + s * HEADS + h] = e;
            denom[g * SLOTS + s * HEADS + h] = e;   // init with self term
        }
    }

    // U_t bf16: U16[g][slot=s*8+h][c]
    {
        const int c = t;
        #pragma unroll
        for (int h = 0; h < HEADS; ++h) {
            float u = 0.f;
            for (int d = 0; d < 32; ++d)
                u += Wk_w[(size_t)(h * 32 + d) * C + c] * qv[h * 32 + d];
            U16[((size_t)g * SLOTS + s * HEADS + h) * C + c] =
                (unsigned short)f2b(u * RSQRT_DH);
        }
    }
}

// ---------------- fused MFMA kernel: QK^T + exp + denom + PV ----------------
__global__ __launch_bounds__(256, 3)
void k_fused(const float* __restrict__ nodes, const unsigned short* __restrict__ U16,
             const int* __restrict__ gstart, float* __restrict__ denom,
             float* __restrict__ Ypart) {
    __shared__ unsigned short lds[LDS_TOT];

    const int g = blockIdx.x / PF, pb = blockIdx.x % PF;
    const int t = threadIdx.x;
    const int wv = t >> 6;        // wave 0..3
    const int l  = t & 63;
    const int lr = l & 15;
    const int q  = l >> 4;

    const int glo = gstart[g], ghi = gstart[g + 1];
    const int len = ghi - glo;
    const int L = (len + PF - 1) / PF;
    const int lo = glo + pb * L;
    const int hi = min(lo + L, ghi);
    const int nr = (hi > lo) ? (hi - lo + RND - 1) / RND : 0;

    // ---- U_t fragments in registers (A-operand, both 16-row tiles) ----
    short8 ureg[2][8];
    {
        const unsigned short* ug = U16 + (size_t)g * SLOTS * C;
        #pragma unroll
        for (int st2 = 0; st2 < 2; ++st2)
            #pragma unroll
            for (int kt = 0; kt < 8; ++kt)
                ureg[st2][kt] = *(const short8*)&ug[(st2 * 16 + lr) * C + q * 8 + kt * 32];
    }

    const floatx4 z4 = {0.f, 0.f, 0.f, 0.f};
    floatx4 yacc[2][4];           // [st][ct]: Y[s=st*16+q*4+r][c=wv*64+ct*16+lr]
    #pragma unroll
    for (int a = 0; a < 2; ++a)
        #pragma unroll
        for (int b = 0; b < 4; ++b) yacc[a][b] = z4;
    float dsum[8];
    #pragma unroll
    for (int i = 0; i < 8; ++i) dsum[i] = 0.f;

    // prefetch round 0 (8 float4 = 32 VGPR)
    float4 xr[CWK];
    if (nr > 0) {
        int base = lo + wv * CWK;
        #pragma unroll
        for (int i = 0; i < CWK; ++i) {
            int gn = base + i;
            xr[i] = (gn < hi) ? *(const float4*)&nodes[(size_t)gn * C + l * 4]
                              : make_float4(0.f, 0.f, 0.f, 0.f);
        }
    }

    for (int rd = 0; rd < nr; ++rd) {
        block_sync_lds();         // prev PV done reading x/e (no vmcnt drain)

        // ---- write x_nc: row r=wv*8+i, swizzled 16B slots: slot^=(r&3) ----
        #pragma unroll
        for (int i = 0; i < CWK; ++i) {
            const int row = wv * CWK + i;
            uint2 w2;
            w2.x = pk_bf16(xr[i].x, xr[i].y);
            w2.y = pk_bf16(xr[i].z, xr[i].w);
            const int off = row * XB + (l >> 3) * 32
                          + ((((l >> 1) & 3) ^ (row & 3)) * 8) + (l & 1) * 4;
            *(uint2*)&lds[X_NC + off] = w2;
        }
        // ---- write x_cn: row c=4l+jj, node-slot wv ^ ((c>>3)&3) ----
        #pragma unroll
        for (int jj = 0; jj < 4; ++jj) {
            const int c = 4 * l + jj;
            const int slot = wv ^ ((c >> 3) & 3);
            uint4 u4;
            u4.x = pk_bf16(fcomp(xr[0], jj), fcomp(xr[1], jj));
            u4.y = pk_bf16(fcomp(xr[2], jj), fcomp(xr[3], jj));
            u4.z = pk_bf16(fcomp(xr[4], jj), fcomp(xr[5], jj));
            u4.w = pk_bf16(fcomp(xr[6], jj), fcomp(xr[7], jj));
            *(uint4*)&lds[X_CN + c * ST + slot * 8] = u4;
        }
        // ---- prefetch next round (in flight across both barriers) ----
        if (rd + 1 < nr) {
            int base = lo + (rd + 1) * RND + wv * CWK;
            #pragma unroll
            for (int i = 0; i < CWK; ++i) {
                int gn = base + i;
                xr[i] = (gn < hi) ? *(const float4*)&nodes[(size_t)gn * C + l * 4]
                                  : make_float4(0.f, 0.f, 0.f, 0.f);
            }
        }

        // ---- QK^T: B rows = x_nc rows wv*8+lr (lr>=8 garbage, masked later) ----
        floatx4 sacc0 = z4, sacc1 = z4;
        {
            const int row = wv * CWK + lr;          // 0..39 (over-read ok, in lds[])
            const int rb = row * XB + ((q ^ (row & 3)) * 8);
            #pragma unroll
            for (int kt = 0; kt < 8; ++kt) {
                short8 bx = *(const short8*)&lds[X_NC + rb + kt * 32];
                sacc0 = __builtin_amdgcn_mfma_f32_16x16x32_bf16(ureg[0][kt], bx, sacc0, 0, 0, 0);
                sacc1 = __builtin_amdgcn_mfma_f32_16x16x32_bf16(ureg[1][kt], bx, sacc1, 0, 0, 0);
            }
        }

        // ---- exp, mask, denom, e_t write (col n = wv*8+lr, lr<8 valid) ----
        {
            const int rbase = lo + rd * RND;
            const bool valid = (lr < 8) && (rbase + wv * CWK + lr < hi);
            const int ncol = wv * CWK + (lr & 7);
            #pragma unroll
            for (int r = 0; r < 4; ++r) {
                float e0 = valid ? __expf(sacc0[r]) : 0.f;
                float e1 = valid ? __expf(sacc1[r]) : 0.f;
                dsum[r]     += e0;
                dsum[4 + r] += e1;
                if (valid) {
                    lds[E_OFF + (q * 4 + r) * EP + ncol]      = (unsigned short)f2b(e0);
                    lds[E_OFF + (16 + q * 4 + r) * EP + ncol] = (unsigned short)f2b(e1);
                } else if (lr < 8) {
                    lds[E_OFF + (q * 4 + r) * EP + ncol]      = 0;
                    lds[E_OFF + (16 + q * 4 + r) * EP + ncol] = 0;
                }
            }
        }
        block_sync_lds();         // all e_t + x_cn visible (vmem still counted)

        // ---- PV: Y[s][c] += e[s][n0..31] * x[n][c]  (single K=32 pair) ----
        {
            short8 pa0 = *(const short8*)&lds[E_OFF + lr * EP + q * 8];
            short8 pa1 = *(const short8*)&lds[E_OFF + (16 + lr) * EP + q * 8];
            #pragma unroll
            for (int ct = 0; ct < 4; ++ct) {
                const int c = wv * 64 + ct * 16 + lr;
                const int slot = q ^ ((c >> 3) & 3);
                short8 bx = *(const short8*)&lds[X_CN + c * ST + slot * 8];
                yacc[0][ct] = __builtin_amdgcn_mfma_f32_16x16x32_bf16(pa0, bx, yacc[0][ct], 0, 0, 0);
                yacc[1][ct] = __builtin_amdgcn_mfma_f32_16x16x32_bf16(pa1, bx, yacc[1][ct], 0, 0, 0);
            }
        }
    }

    // ---- flush Y partials (zero-fills when nr==0) ----
    {
        float* yg = &Ypart[(((size_t)g * PF + pb) * SLOTS) * C];
        #pragma unroll
        for (int st = 0; st < 2; ++st)
            #pragma unroll
            for (int ct = 0; ct < 4; ++ct)
                #pragma unroll
                for (int r = 0; r < 4; ++r)
                    yg[(st * 16 + q * 4 + r) * C + wv * 64 + ct * 16 + lr] = yacc[st][ct][r];
    }

    // ---- denom: reduce over 16 lanes (n-direction), atomics from lr==0 ----
    #pragma unroll
    for (int i = 0; i < 8; ++i) {
        float v = dsum[i];
        v += __shfl_xor(v, 1);
        v += __shfl_xor(v, 2);
        v += __shfl_xor(v, 4);
        v += __shfl_xor(v, 8);
        dsum[i] = v;
    }
    if (lr == 0 && nr > 0) {
        #pragma unroll
        for (int mt = 0; mt < 2; ++mt)
            #pragma unroll
            for (int r = 0; r < 4; ++r)
                atomicAdd(&denom[g * SLOTS + mt * 16 + q * 4 + r], dsum[mt * 4 + r]);
    }
}

// ---------------- epilogue: out = LN(elu(Wv*(Ysum/denom + cself*x) + bv) + stars)
__global__ void k_epilogue(const float* __restrict__ stars,
                           const float* __restrict__ Wv_w, const float* __restrict__ Wv_b,
                           const float* __restrict__ gamma, const float* __restrict__ beta,
                           const float* __restrict__ Ypart, const float* __restrict__ eself,
                           const float* __restrict__ denom, float* __restrict__ out) {
    __shared__ float xs[C];
    __shared__ float yl[HEADS * C];
    __shared__ float cs[HEADS], ivd[HEADS], scl[HEADS];
    __shared__ float rb[8];

    const int gs = blockIdx.x;
    const int g = gs >> 2, s = gs & 3;
    const int t = threadIdx.x;

    xs[t] = stars[gs * C + t];
    if (t < HEADS) {
        float dn = denom[g * SLOTS + s * HEADS + t];
        float iv = 1.f / (dn + 1e-16f);
        ivd[t] = iv;
        cs[t] = eself[g * SLOTS + s * HEADS + t] * iv;
        scl[t] = dn * iv;
    }
    __syncthreads();

    for (int i = t; i < HEADS * C; i += 256) {
        int h = i >> 8, j = i & 255;
        float sum = 0.f;
        #pragma unroll
        for (int pbi = 0; pbi < PF; ++pbi)
            sum += Ypart[(((size_t)g * PF + pbi) * SLOTS + s * HEADS + h) * C + j];
        yl[i] = sum * ivd[h] + cs[h] * xs[j];
    }
    __syncthreads();

    const int c = t, h = c >> 5;
    float a = 0.f;
    const float* wv = Wv_w + (size_t)c * C;
    const float* yh = &yl[h * C];
    #pragma unroll 4
    for (int j = 0; j < C; j += 4) {
        float4 w4 = *(const float4*)(wv + j);
        float4 y4 = *(const float4*)(yh + j);
        a += w4.x * y4.x + w4.y * y4.y + w4.z * y4.z + w4.w * y4.w;
    }
    a += Wv_b[c] * scl[h];

    float v = a > 0.f ? a : (__expf(a) - 1.f);     // ELU
    float r = v + xs[c];                            // residual

    float ssum = r;
    #pragma unroll
    for (int off = 32; off; off >>= 1) ssum += __shfl_down(ssum, off, 64);
    const int wid = t >> 6, lane = t & 63;
    if (lane == 0) rb[wid] = ssum;
    __syncthreads();
    const float mu = (rb[0] + rb[1] + rb[2] + rb[3]) * (1.f / 256.f);
    const float d = r - mu;
    float vsum = d * d;
    #pragma unroll
    for (int off = 32; off; off >>= 1) vsum += __shfl_down(vsum, off, 64);
    if (lane == 0) rb[4 + wid] = vsum;
    __syncthreads();
    const float var = (rb[4] + rb[5] + rb[6] + rb[7]) * (1.f / 256.f);
    out[gs * C + c] = d * rsqrtf(var + LN_EPS) * gamma[c] + beta[c];
}

// ---------------------------------------------------------------------------
extern "C" void kernel_launch(void* const* d_in, const int* in_sizes, int n_in,
                              void* d_out, int out_size, void* d_ws, size_t ws_size,
                              hipStream_t stream) {
    const float* stars = (const float*)d_in[0];
    const float* nodes = (const float*)d_in[1];
    const int*   batch = (const int*)d_in[2];
    const float* Wq_w  = (const float*)d_in[3];
    const float* Wq_b  = (const float*)d_in[4];
    const float* Wk_w  = (const float*)d_in[5];
    const float* Wk_b  = (const float*)d_in[6];
    const float* Wv_w  = (const float*)d_in[7];
    const float* Wv_b  = (const float*)d_in[8];
    const float* gamma = (const float*)d_in[9];
    const float* beta  = (const float*)d_in[10];

    const int N = in_sizes[1] / C;
    const int G = in_sizes[0] / (NUM_STAR * C);

    unsigned short* U16 = (unsigned short*)d_ws;                    // G*SLOTS*C ush
    float* eself = (float*)((char*)d_ws + (size_t)G * SLOTS * C * 2);
    float* denom = eself + (size_t)G * SLOTS;
    float* Ypart = denom + (size_t)G * SLOTS;                       // G*PF*SLOTS*C f32
    int*   gstart = (int*)(Ypart + (size_t)G * PF * SLOTS * C);     // G+1

    float* out = (float*)d_out;

    k_star_prep<<<G * NUM_STAR + 1, 256, 0, stream>>>(stars, Wq_w, Wq_b, Wk_w, Wk_b,
                                                      U16, eself, denom,
                                                      batch, N, G, gstart);
    k_fused<<<G * PF, 256, 0, stream>>>(nodes, U16, gstart, denom, Ypart);
    k_epilogue<<<G * NUM_STAR, 256, 0, stream>>>(stars, Wv_w, Wv_b, gamma, beta,
                                                 Ypart, eself, denom, out);
}

// Round 8
// 71.350 us; speedup vs baseline: 1.1734x; 1.1734x over previous
//
#include <hip/hip_runtime.h>
#include <math.h>

#define HEADS 8
#define C 256
#define NUM_STAR 4
#define SLOTS 32              // NUM_STAR * HEADS
#define RSQRT_DH 0.17677669529663688f   // 1/sqrt(32)
#define LN_EPS 1e-5f
#define PF 24                 // partitions per graph (grid = G*PF = 768 = 3/CU)
#define NT 16                 // nodes per round (block-wide)
#define FS 260                // f32 tile row stride (1040 B, 16B-mult, odd 16B-units)
#define ES 24                 // e row stride (ushorts, 48 B)

typedef __attribute__((ext_vector_type(8))) short short8;    // bf16x8 MFMA operand
typedef __attribute__((ext_vector_type(4))) float floatx4;   // f32x4 MFMA accum

typedef const unsigned int __attribute__((address_space(1)))* gp1_t;
typedef unsigned int __attribute__((address_space(3)))* lp3_t;

// f32 -> bf16 (RNE) top-16 (scalar)
__device__ __forceinline__ unsigned int f2b(float f) {
    unsigned int u = __float_as_uint(f);
    return (u + 0x7fffu + ((u >> 16) & 1u)) >> 16;
}
// packed f32x2 -> bf16x2 (RNE): lo -> [15:0], hi -> [31:16]
__device__ __forceinline__ unsigned int pk_bf16(float lo, float hi) {
    unsigned int r;
    asm("v_cvt_pk_bf16_f32 %0, %1, %2" : "=v"(r) : "v"(lo), "v"(hi));
    return r;
}
// async global->LDS, 16B per lane; ldst base wave-uniform, src per-lane
__device__ __forceinline__ void gld_lds16(const float* g, float* l) {
    __builtin_amdgcn_global_load_lds((gp1_t)(const void*)g, (lp3_t)(void*)l, 16, 0, 0);
}
// raw barrier: LDS-visible, does NOT drain vmcnt
__device__ __forceinline__ void block_sync_lds() {
    asm volatile("s_waitcnt lgkmcnt(0)" ::: "memory");
    __builtin_amdgcn_sched_barrier(0);
    __builtin_amdgcn_s_barrier();
    __builtin_amdgcn_sched_barrier(0);
}

// ---------------- star prep (+ gstart fold in last block) -------------------
__global__ void k_star_prep(const float* __restrict__ stars,
                            const float* __restrict__ Wq_w, const float* __restrict__ Wq_b,
                            const float* __restrict__ Wk_w, const float* __restrict__ Wk_b,
                            unsigned short* __restrict__ U16, float* __restrict__ eself,
                            float* __restrict__ denom,
                            const int* __restrict__ batch, int N, int G,
                            int* __restrict__ gstart) {
    if (blockIdx.x == gridDim.x - 1) {       // gstart block
        int g = threadIdx.x;
        if (g > G) return;
        if (g == 0) { gstart[0] = 0; return; }
        if (g == G) { gstart[G] = N; return; }
        int lo = 0, hi = N;
        while (lo < hi) {
            int mid = (lo + hi) >> 1;
            if (batch[mid] < g) lo = mid + 1; else hi = mid;
        }
        gstart[g] = lo;
        return;
    }

    __shared__ float xs[C];
    __shared__ float qv[C];
    __shared__ float kv[C];
    const int gs = blockIdx.x;           // g*4 + s
    const int g = gs >> 2, s = gs & 3;
    const int t = threadIdx.x;

    xs[t] = stars[gs * C + t];
    __syncthreads();

    float aq = Wq_b[t], ak = Wk_b[t];
    const float* wq = Wq_w + (size_t)t * C;
    const float* wk = Wk_w + (size_t)t * C;
    #pragma unroll 4
    for (int j = 0; j < C; j += 4) {
        float4 x4 = *(const float4*)(xs + j);
        float4 a4 = *(const float4*)(wq + j);
        aq += a4.x * x4.x + a4.y * x4.y + a4.z * x4.z + a4.w * x4.w;
        float4 b4 = *(const float4*)(wk + j);
        ak += b4.x * x4.x + b4.y * x4.y + b4.z * x4.z + b4.w * x4.w;
    }
    qv[t] = aq; kv[t] = ak;
    __syncthreads();

    {   // self score per head
        float p = qv[t] * kv[t];
        #pragma unroll
        for (int off = 16; off; off >>= 1) p += __shfl_down(p, off, 32);
        if ((t & 31) == 0) {
            int h = t >> 5;
            float e = __expf(p * RSQRT_DH);
            eself[g * SLOTS + s * HEADS + h] = e;
            denom[g * SLOTS + s * HEADS + h] = e;   // init with self term
        }
    }

    // U_t bf16: U16[g][slot=s*8+h][c]  (d-loop unrolled -> independent loads)
    {
        const int c = t;
        #pragma unroll
        for (int h = 0; h < HEADS; ++h) {
            float u = 0.f;
            #pragma unroll
            for (int d = 0; d < 32; ++d)
                u += Wk_w[(size_t)(h * 32 + d) * C + c] * qv[h * 32 + d];
            U16[((size_t)g * SLOTS + s * HEADS + h) * C + c] =
                (unsigned short)f2b(u * RSQRT_DH);
        }
    }
}

// ---------------- fused MFMA kernel: QK^T + exp + denom + PV ----------------
// Triple-buffered f32 node tile via global_load_lds, 2-round prefetch depth.
__global__ __launch_bounds__(256, 3)
void k_fused(const float* __restrict__ nodes, const unsigned short* __restrict__ U16,
             const int* __restrict__ gstart, float* __restrict__ denom,
             float* __restrict__ Ypart) {
    __shared__ float          fbuf[3 * NT * FS];   // 49,920 B  f32 [slot3][n][c]
    __shared__ unsigned short e_lds[SLOTS * ES];   //  1,536 B  [s][n]

    const int g = blockIdx.x / PF, pb = blockIdx.x % PF;
    const int t = threadIdx.x;
    const int wv = t >> 6;        // wave 0..3
    const int l  = t & 63;
    const int lr = l & 15;
    const int q  = l >> 4;

    const int glo = gstart[g], ghi = gstart[g + 1];
    const int len = ghi - glo;
    const int L = (len + PF - 1) / PF;
    const int lo = glo + pb * L;
    const int hi = min(lo + L, ghi);
    const int nr = (hi > lo) ? (hi - lo + NT - 1) / NT : 0;

    const floatx4 z4 = {0.f, 0.f, 0.f, 0.f};
    floatx4 yacc[2][4];           // [st][ct]: Y[st*16+q*4+r][wv*64+ct*16+lr]
    #pragma unroll
    for (int a = 0; a < 2; ++a)
        #pragma unroll
        for (int b = 0; b < 4; ++b) yacc[a][b] = z4;

    if (nr > 0) {
        // ---- U_t fragments: wave wv<2 owns slot-tile st=wv (16 slots) ----
        short8 ureg[8];
        if (wv < 2) {
            const unsigned short* ug = U16 + (size_t)g * SLOTS * C;
            #pragma unroll
            for (int kt = 0; kt < 8; ++kt)
                ureg[kt] = *(const short8*)&ug[(wv * 16 + lr) * C + q * 8 + kt * 32];
        }
        asm volatile("s_waitcnt vmcnt(0)" ::: "memory");   // deterministic baseline

        float dsum[4];
        #pragma unroll
        for (int i = 0; i < 4; ++i) dsum[i] = 0.f;

        // issue round r's 4 per-wave rows into fbuf slot r%3 (clamped dup past end)
        auto issue = [&](int r) {
            const int slot = r % 3;
            #pragma unroll
            for (int i = 0; i < 4; ++i) {
                int node = wv * 4 + i;
                int gn = lo + r * NT + node;
                if (gn >= hi) gn = lo;                     // harmless dup (e=0 kills it)
                gld_lds16(nodes + (size_t)gn * C + l * 4,
                          &fbuf[(slot * NT + node) * FS]);
            }
        };

        issue(0);
        issue(1);

        for (int rd = 0; rd < nr; ++rd) {
            block_sync_lds();         // prev PV done; fbuf slot (rd+2)%3 reusable
            issue(rd + 2);            // always (clamped) -> uniform vmcnt arithmetic
            asm volatile("s_waitcnt vmcnt(8)" ::: "memory");  // rd's tile landed
            __builtin_amdgcn_sched_barrier(0);
            __builtin_amdgcn_s_barrier();                     // ALL waves' rows landed

            const float* fb = &fbuf[(rd % 3) * NT * FS];

            // ---- QK^T: wave wv<2 computes slot-tile st=wv over 16 nodes ----
            if (wv < 2) {
                floatx4 sacc = z4;
                const float* xr = fb + lr * FS + q * 8;
                #pragma unroll
                for (int kt = 0; kt < 8; ++kt) {
                    float4 a4 = *(const float4*)(xr + kt * 32);
                    float4 b4 = *(const float4*)(xr + kt * 32 + 4);
                    short8 bx;
                    ((unsigned int*)&bx)[0] = pk_bf16(a4.x, a4.y);
                    ((unsigned int*)&bx)[1] = pk_bf16(a4.z, a4.w);
                    ((unsigned int*)&bx)[2] = pk_bf16(b4.x, b4.y);
                    ((unsigned int*)&bx)[3] = pk_bf16(b4.z, b4.w);
                    sacc = __builtin_amdgcn_mfma_f32_16x16x32_bf16(ureg[kt], bx, sacc, 0, 0, 0);
                }
                const bool valid = (lo + rd * NT + lr) < hi;   // this lane's node col
                #pragma unroll
                for (int r = 0; r < 4; ++r) {
                    float ev = valid ? __expf(sacc[r]) : 0.f;
                    dsum[r] += ev;
                    e_lds[(wv * 16 + q * 4 + r) * ES + lr] = (unsigned short)f2b(ev);
                }
            }
            block_sync_lds();         // e ready for all waves

            // ---- PV: all waves; K=32 with upper 16 k zeroed (16-node window) ----
            short8 pa0, pa1;
            if (l < 32) {
                pa0 = *(const short8*)&e_lds[lr * ES + q * 8];
                pa1 = *(const short8*)&e_lds[(16 + lr) * ES + q * 8];
            } else {
                #pragma unroll
                for (int j = 0; j < 8; ++j) { pa0[j] = 0; pa1[j] = 0; }
            }
            #pragma unroll
            for (int ct = 0; ct < 4; ++ct) {
                short8 bx;
                if (l < 32) {
                    const float* col = fb + q * 8 * FS + wv * 64 + ct * 16 + lr;
                    ((unsigned int*)&bx)[0] = pk_bf16(col[0 * FS], col[1 * FS]);
                    ((unsigned int*)&bx)[1] = pk_bf16(col[2 * FS], col[3 * FS]);
                    ((unsigned int*)&bx)[2] = pk_bf16(col[4 * FS], col[5 * FS]);
                    ((unsigned int*)&bx)[3] = pk_bf16(col[6 * FS], col[7 * FS]);
                } else {
                    #pragma unroll
                    for (int j = 0; j < 8; ++j) bx[j] = 0;
                }
                yacc[0][ct] = __builtin_amdgcn_mfma_f32_16x16x32_bf16(pa0, bx, yacc[0][ct], 0, 0, 0);
                yacc[1][ct] = __builtin_amdgcn_mfma_f32_16x16x32_bf16(pa1, bx, yacc[1][ct], 0, 0, 0);
            }
        }

        // ---- denom: reduce over 16 node-lanes, atomics from lr==0 of wv<2 ----
        if (wv < 2) {
            #pragma unroll
            for (int i = 0; i < 4; ++i) {
                float v = dsum[i];
                v += __shfl_xor(v, 1);
                v += __shfl_xor(v, 2);
                v += __shfl_xor(v, 4);
                v += __shfl_xor(v, 8);
                dsum[i] = v;
            }
            if (lr == 0) {
                #pragma unroll
                for (int r = 0; r < 4; ++r)
                    atomicAdd(&denom[g * SLOTS + wv * 16 + q * 4 + r], dsum[r]);
            }
        }
    }

    // ---- flush Y partials (zero-fills when nr==0) ----
    {
        float* yg = &Ypart[(((size_t)g * PF + pb) * SLOTS) * C];
        #pragma unroll
        for (int st = 0; st < 2; ++st)
            #pragma unroll
            for (int ct = 0; ct < 4; ++ct)
                #pragma unroll
                for (int r = 0; r < 4; ++r)
                    yg[(st * 16 + q * 4 + r) * C + wv * 64 + ct * 16 + lr] = yacc[st][ct][r];
    }
}

// ---------------- epilogue: out = LN(elu(Wv*(Ysum/denom + cself*x) + bv) + stars)
__global__ void k_epilogue(const float* __restrict__ stars,
                           const float* __restrict__ Wv_w, const float* __restrict__ Wv_b,
                           const float* __restrict__ gamma, const float* __restrict__ beta,
                           const float* __restrict__ Ypart, const float* __restrict__ eself,
                           const float* __restrict__ denom, float* __restrict__ out) {
    __shared__ float xs[C];
    __shared__ float yl[HEADS * C];
    __shared__ float cs[HEADS], ivd[HEADS], scl[HEADS];
    __shared__ float rb[8];

    const int gs = blockIdx.x;
    const int g = gs >> 2, s = gs & 3;
    const int t = threadIdx.x;

    xs[t] = stars[gs * C + t];
    if (t < HEADS) {
        float dn = denom[g * SLOTS + s * HEADS + t];
        float iv = 1.f / (dn + 1e-16f);
        ivd[t] = iv;
        cs[t] = eself[g * SLOTS + s * HEADS + t] * iv;
        scl[t] = dn * iv;
    }
    __syncthreads();

    for (int i = t; i < HEADS * C; i += 256) {
        int h = i >> 8, j = i & 255;
        float sum = 0.f;
        #pragma unroll
        for (int pbi = 0; pbi < PF; ++pbi)
            sum += Ypart[(((size_t)g * PF + pbi) * SLOTS + s * HEADS + h) * C + j];
        yl[i] = sum * ivd[h] + cs[h] * xs[j];
    }
    __syncthreads();

    const int c = t, h = c >> 5;
    float a = 0.f;
    const float* wv = Wv_w + (size_t)c * C;
    const float* yh = &yl[h * C];
    #pragma unroll 4
    for (int j = 0; j < C; j += 4) {
        float4 w4 = *(const float4*)(wv + j);
        float4 y4 = *(const float4*)(yh + j);
        a += w4.x * y4.x + w4.y * y4.y + w4.z * y4.z + w4.w * y4.w;
    }
    a += Wv_b[c] * scl[h];

    float v = a > 0.f ? a : (__expf(a) - 1.f);     // ELU
    float r = v + xs[c];                            // residual

    float ssum = r;
    #pragma unroll
    for (int off = 32; off; off >>= 1) ssum += __shfl_down(ssum, off, 64);
    const int wid = t >> 6, lane = t & 63;
    if (lane == 0) rb[wid] = ssum;
    __syncthreads();
    const float mu = (rb[0] + rb[1] + rb[2] + rb[3]) * (1.f / 256.f);
    const float d = r - mu;
    float vsum = d * d;
    #pragma unroll
    for (int off = 32; off; off >>= 1) vsum += __shfl_down(vsum, off, 64);
    if (lane == 0) rb[4 + wid] = vsum;
    __syncthreads();
    const float var = (rb[4] + rb[5] + rb[6] + rb[7]) * (1.f / 256.f);
    out[gs * C + c] = d * rsqrtf(var + LN_EPS) * gamma[c] + beta[c];
}

// ---------------------------------------------------------------------------
extern "C" void kernel_launch(void* const* d_in, const int* in_sizes, int n_in,
                              void* d_out, int out_size, void* d_ws, size_t ws_size,
                              hipStream_t stream) {
    const float* stars = (const float*)d_in[0];
    const float* nodes = (const float*)d_in[1];
    const int*   batch = (const int*)d_in[2];
    const float* Wq_w  = (const float*)d_in[3];
    const float* Wq_b  = (const float*)d_in[4];
    const float* Wk_w  = (const float*)d_in[5];
    const float* Wk_b  = (const float*)d_in[6];
    const float* Wv_w  = (const float*)d_in[7];
    const float* Wv_b  = (const float*)d_in[8];
    const float* gamma = (const float*)d_in[9];
    const float* beta  = (const float*)d_in[10];

    const int N = in_sizes[1] / C;
    const int G = in_sizes[0] / (NUM_STAR * C);

    unsigned short* U16 = (unsigned short*)d_ws;                    // G*SLOTS*C ush
    float* eself = (float*)((char*)d_ws + (size_t)G * SLOTS * C * 2);
    float* denom = eself + (size_t)G * SLOTS;
    float* Ypart = denom + (size_t)G * SLOTS;                       // G*PF*SLOTS*C f32
    int*   gstart = (int*)(Ypart + (size_t)G * PF * SLOTS * C);     // G+1

    float* out = (float*)d_out;

    k_star_prep<<<G * NUM_STAR + 1, 256, 0, stream>>>(stars, Wq_w, Wq_b, Wk_w, Wk_b,
                                                      U16, eself, denom,
                                                      batch, N, G, gstart);
    k_fused<<<G * PF, 256, 0, stream>>>(nodes, U16, gstart, denom, Ypart);
    k_epilogue<<<G * NUM_STAR, 256, 0, stream>>>(stars, Wv_w, Wv_b, gamma, beta,
                                                 Ypart, eself, denom, out);
}